// Round 16
// baseline (3196.019 us; speedup 1.0000x reference)
//
#include <hip/hip_runtime.h>
#include <hip/hip_bf16.h>

#define SEQ 512
#define BATCH 64
#define IN_DIM 512
#define HID 1024
#define G3 3072          // 3*HID
#define MTOT 32768       // SEQ*BATCH
#define GB 16            // batches per super-group (4 super-groups)
#define UPW 32           // hidden units per WG

typedef float f32x4 __attribute__((ext_vector_type(4)));
typedef short s16x8 __attribute__((ext_vector_type(8)));

static __device__ __forceinline__ unsigned short f2bf(float f) {
  union { float f; unsigned u; } v; v.f = f;
  unsigned r = v.u + 0x7fffu + ((v.u >> 16) & 1u);
  return (unsigned short)(r >> 16);
}
static __device__ __forceinline__ float bf2f(unsigned short b) {
  union { unsigned u; float f; } v; v.u = ((unsigned)b) << 16;
  return v.f;
}
static __device__ __forceinline__ unsigned umin2(unsigned a, unsigned b) { return a < b ? a : b; }

// ---------------- fp32 -> bf16 hi/lo split ----------------
__global__ __launch_bounds__(256) void split_kernel(const float* __restrict__ src,
    unsigned short* __restrict__ hi, unsigned short* __restrict__ lo, int n4) {
  int stride = gridDim.x * blockDim.x;
  for (int i = blockIdx.x * blockDim.x + threadIdx.x; i < n4; i += stride) {
    float4 v = ((const float4*)src)[i];
    ushort4 h, l;
    h.x = f2bf(v.x); l.x = f2bf(v.x - bf2f(h.x));
    h.y = f2bf(v.y); l.y = f2bf(v.y - bf2f(h.y));
    h.z = f2bf(v.z); l.z = f2bf(v.z - bf2f(h.z));
    h.w = f2bf(v.w); l.w = f2bf(v.w - bf2f(h.w));
    ((ushort4*)hi)[i] = h;
    ((ushort4*)lo)[i] = l;
  }
}

// ---------------- fused cooperative kernel ----------------
// 256 WGs x 512 thr, 1 WG/CU (LDS pin). Roles by blockIdx (round-14 proven):
//   WGs 0-127: scan. WGs 128-255: gi GEMM workers (s-major jobs).
// Scan: 4 super-groups x 32 WGs; each super-group's 16 batches split into TWO
// 8-batch sub-groups A/B with SEPARATE barriers (same relaxed-monotonic
// pattern). Each WG alternates A(s) -> arrive A -> B(s) -> arrive B, so each
// sub-barrier's ~2us latency hides under the other sub's compute. M=8 of the
// MFMA tile wasted (rows 8-15 duplicate rows 0-7; same L2 lines).

#define LDH(dst, OFFS) asm volatile("global_load_dwordx4 %0, %1, off offset:" OFFS " sc0 sc1" : "=v"(dst) : "v"(hadr))
#define WAITV(N) do { asm volatile("s_waitcnt vmcnt(" #N ")" ::: "memory"); __builtin_amdgcn_sched_barrier(0); } while (0)

__global__ __launch_bounds__(512, 2) void gru_fused(
    const unsigned short* __restrict__ Whh_hi,
    const unsigned short* __restrict__ emb_hi, const unsigned short* __restrict__ emb_lo,
    const unsigned short* __restrict__ wih_hi, const unsigned short* __restrict__ wih_lo,
    const float* __restrict__ bih,
    float* __restrict__ gi32, unsigned short* __restrict__ gi16, int gi_is_f32,
    const float* __restrict__ bhh,
    unsigned short* __restrict__ h0, unsigned short* __restrict__ h1,
    unsigned* __restrict__ bar,
    float* __restrict__ out, float* __restrict__ hidden)
{
  __shared__ float ghp[8][8][100];         // 25.6KB (scan role)
  __shared__ unsigned short Ah[128 * 64];  // 4x16KB (gemm role) -> ~90KB total
  __shared__ unsigned short Alo_[128 * 64];
  __shared__ unsigned short Bh[128 * 64];
  __shared__ unsigned short Blo_[128 * 64];
  const int tid = threadIdx.x;
  const int wg = blockIdx.x;
  const int wave = tid >> 6, lane = tid & 63;
  const int row16 = lane & 15;

  unsigned* cnt = bar;                 // [0..255] slab counters (device scope)
  unsigned* cA = bar + 256;            // 16 arrive counters, 128B apart
  unsigned* genv = bar + 768;          // 8 gen pairs, genv[(g*2+sub)*32 + half]

  if (wg >= 128) {
    // ================= GEMM worker role (identical to round 14) ============
    const int widx = wg - 128;
    const int wm = (wave >> 2) * 64, wn = (wave & 3) * 32;
    const int kq = lane >> 4;
    const int srow = tid >> 3;
    const int skc = tid & 7;

    for (int it = 0; it < 48; ++it) {
      int q = widx + it * 128;
      int bm = q / 24, bn = q - bm * 24;
      int bm0 = bm * 128, bn0 = bn * 128;

      f32x4 acc[4][2] = {};
      for (int kt = 0; kt < IN_DIM / 64; ++kt) {
        uint4 rah[2], ral[2], rbh[2], rbl[2];
        for (int i = 0; i < 2; ++i) {
          int r = i * 64 + srow;
          size_t ao = (size_t)(bm0 + r) * IN_DIM + kt * 64 + skc * 8;
          size_t bo = (size_t)(bn0 + r) * IN_DIM + kt * 64 + skc * 8;
          rah[i] = *(const uint4*)&emb_hi[ao];
          ral[i] = *(const uint4*)&emb_lo[ao];
          rbh[i] = *(const uint4*)&wih_hi[bo];
          rbl[i] = *(const uint4*)&wih_lo[bo];
        }
        __syncthreads();
        for (int i = 0; i < 2; ++i) {
          int r = i * 64 + srow;
          *(uint4*)&Ah[r * 64 + skc * 8]   = rah[i];
          *(uint4*)&Alo_[r * 64 + skc * 8] = ral[i];
          *(uint4*)&Bh[r * 64 + skc * 8]   = rbh[i];
          *(uint4*)&Blo_[r * 64 + skc * 8] = rbl[i];
        }
        __syncthreads();
        for (int kk = 0; kk < 2; ++kk) {
          s16x8 ah[4], al[4], bh[2], bl[2];
          for (int mi = 0; mi < 4; ++mi) {
            int off = (wm + mi * 16 + row16) * 64 + kk * 32 + kq * 8;
            ah[mi] = *(const s16x8*)&Ah[off];
            al[mi] = *(const s16x8*)&Alo_[off];
          }
          for (int ni = 0; ni < 2; ++ni) {
            int off = (wn + ni * 16 + row16) * 64 + kk * 32 + kq * 8;
            bh[ni] = *(const s16x8*)&Bh[off];
            bl[ni] = *(const s16x8*)&Blo_[off];
          }
          for (int mi = 0; mi < 4; ++mi)
            for (int ni = 0; ni < 2; ++ni) {
              acc[mi][ni] = __builtin_amdgcn_mfma_f32_16x16x32_bf16(ah[mi], bh[ni], acc[mi][ni], 0, 0, 0);
              acc[mi][ni] = __builtin_amdgcn_mfma_f32_16x16x32_bf16(al[mi], bh[ni], acc[mi][ni], 0, 0, 0);
              acc[mi][ni] = __builtin_amdgcn_mfma_f32_16x16x32_bf16(ah[mi], bl[ni], acc[mi][ni], 0, 0, 0);
            }
        }
      }
      for (int mi = 0; mi < 4; ++mi) {
        int grow0 = bm0 + wm + mi * 16 + kq * 4;
        for (int ni = 0; ni < 2; ++ni) {
          int gcol = bn0 + wn + ni * 16 + row16;
          float bias = bih[gcol];
#pragma unroll
          for (int qq = 0; qq < 4; ++qq) {
            float v = acc[mi][ni][qq] + bias;
            size_t off = (size_t)(grow0 + qq) * G3 + gcol;
            if (gi_is_f32) {
              unsigned long long ad = (unsigned long long)(gi32 + off);
              asm volatile("global_store_dword %0, %1, off sc0 sc1" :: "v"(ad), "v"(v) : "memory");
            } else {
              unsigned short bv = f2bf(v);
              unsigned long long ad = (unsigned long long)(gi16 + off);
              asm volatile("global_store_short %0, %1, off sc0 sc1" :: "v"(ad), "v"(bv) : "memory");
            }
          }
        }
      }
      asm volatile("s_waitcnt vmcnt(0)" ::: "memory");
      __syncthreads();
      if (tid == 0)
        __hip_atomic_fetch_add(&cnt[bm], 1u, __ATOMIC_RELAXED, __HIP_MEMORY_SCOPE_AGENT);
    }
    return;
  }

  // ================= scan role: A/B sub-group pipeline =================
  const int g = wg >> 5, w = wg & 31;
  const int j0 = w * UPW;
  const int kw = wave;
  const int koc = lane >> 4;

  // hoist this lane's W fragments: 6 col-tiles x 4 k-chunks, global -> VGPR
  s16x8 wr[24];
#pragma unroll
  for (int t = 0; t < 6; ++t) {
#pragma unroll
    for (int ck = 0; ck < 4; ++ck) {
      int wrow = (t >> 1) * HID + j0 + (t & 1) * 16 + row16;
      size_t byte = (size_t)wrow * 2048 + (size_t)(kw * 256 + ck * 64 + koc * 16);
      wr[t * 4 + ck] = *(const s16x8*)((const char*)Whh_hi + byte);
    }
  }

  const int bA = g * GB, bB = g * GB + 8;
  const unsigned hvA = (unsigned)((bA + (row16 & 7)) * 2048 + kw * 256 + koc * 16);
  const unsigned hvB = (unsigned)((bB + (row16 & 7)) * 2048 + kw * 256 + koc * 16);
  const int bb_l = tid >> 5, uu_l = tid & 31;   // valid for tid<256
  const bool gat = (tid < 256);
  const int jg = j0 + uu_l;
  float bh_r = 0.f, bh_z = 0.f, bh_n = 0.f;
  if (gat) { bh_r = bhh[jg]; bh_z = bhh[HID + jg]; bh_n = bhh[2 * HID + jg]; }
  float hprevA = 0.f, hprevB = 0.f;
  const int half = w >> 4;

  for (int s = 0; s < SEQ; ++s) {
    const unsigned short* hin = (s & 1) ? h1 : h0;
    unsigned short* hout = (s & 1) ? h0 : h1;

    // ---- wait A: slab (even s only, monotonic) + gen_A pair ----
    if (tid == 0) {
      if ((s & 1) == 0) {
        unsigned long long cva = (unsigned long long)(cnt + (s >> 1));
        for (;;) {
          unsigned cc;
          asm volatile("global_load_dword %0, %1, off sc0 sc1\n\ts_waitcnt vmcnt(0)"
                       : "=v"(cc) : "v"(cva) : "memory");
          if (cc >= 24u) break;
        }
      }
      unsigned long long gva = (unsigned long long)(genv + (g * 2 + 0) * 32);
      for (;;) {
        uint2 gg;
        asm volatile("global_load_dwordx2 %0, %1, off sc0 sc1\n\ts_waitcnt vmcnt(0)"
                     : "=v"(gg) : "v"(gva) : "memory");
        if (umin2(gg.x, gg.y) >= (unsigned)s) break;
      }
    }
    __syncthreads();

    // gi loads for BOTH subs (gating threads), retire inside A's WAITV(3)
    float girA = 0.f, gizA = 0.f, ginA = 0.f, girB = 0.f, gizB = 0.f, ginB = 0.f;
    unsigned short r16A = 0, z16A = 0, n16A = 0, r16B = 0, z16B = 0, n16B = 0;
    if (gat) {
      if (gi_is_f32) {
        unsigned long long gaA = (unsigned long long)(gi32 + (size_t)(s * BATCH + bA + bb_l) * G3 + jg);
        unsigned long long gaB = (unsigned long long)(gi32 + (size_t)(s * BATCH + bB + bb_l) * G3 + jg);
        asm volatile("global_load_dword %0, %1, off sc0 sc1" : "=v"(girA) : "v"(gaA));
        asm volatile("global_load_dword %0, %1, off sc0 sc1" : "=v"(gizA) : "v"(gaA + 4096ull));
        asm volatile("global_load_dword %0, %1, off sc0 sc1" : "=v"(ginA) : "v"(gaA + 8192ull));
        asm volatile("global_load_dword %0, %1, off sc0 sc1" : "=v"(girB) : "v"(gaB));
        asm volatile("global_load_dword %0, %1, off sc0 sc1" : "=v"(gizB) : "v"(gaB + 4096ull));
        asm volatile("global_load_dword %0, %1, off sc0 sc1" : "=v"(ginB) : "v"(gaB + 8192ull));
      } else {
        unsigned long long gaA = (unsigned long long)(gi16 + (size_t)(s * BATCH + bA + bb_l) * G3 + jg);
        unsigned long long gaB = (unsigned long long)(gi16 + (size_t)(s * BATCH + bB + bb_l) * G3 + jg);
        asm volatile("global_load_ushort %0, %1, off sc0 sc1" : "=v"(r16A) : "v"(gaA));
        asm volatile("global_load_ushort %0, %1, off sc0 sc1" : "=v"(z16A) : "v"(gaA + 2048ull));
        asm volatile("global_load_ushort %0, %1, off sc0 sc1" : "=v"(n16A) : "v"(gaA + 4096ull));
        asm volatile("global_load_ushort %0, %1, off sc0 sc1" : "=v"(r16B) : "v"(gaB));
        asm volatile("global_load_ushort %0, %1, off sc0 sc1" : "=v"(z16B) : "v"(gaB + 2048ull));
        asm volatile("global_load_ushort %0, %1, off sc0 sc1" : "=v"(n16B) : "v"(gaB + 4096ull));
      }
    }

    // ---- sub A: compute + store + arrive ----
    {
      unsigned long long hadr = (unsigned long long)hin + hvA;
      f32x4 acc[6] = {};
      s16x8 a0, a1, a2, a3;
      LDH(a0, "0"); LDH(a1, "64"); LDH(a2, "128"); LDH(a3, "192");
      WAITV(3);
#pragma unroll
      for (int t = 0; t < 6; ++t) acc[t] = __builtin_amdgcn_mfma_f32_16x16x32_bf16(a0, wr[t * 4 + 0], acc[t], 0, 0, 0);
      WAITV(2);
#pragma unroll
      for (int t = 0; t < 6; ++t) acc[t] = __builtin_amdgcn_mfma_f32_16x16x32_bf16(a1, wr[t * 4 + 1], acc[t], 0, 0, 0);
      WAITV(1);
#pragma unroll
      for (int t = 0; t < 6; ++t) acc[t] = __builtin_amdgcn_mfma_f32_16x16x32_bf16(a2, wr[t * 4 + 2], acc[t], 0, 0, 0);
      WAITV(0);
#pragma unroll
      for (int t = 0; t < 6; ++t) acc[t] = __builtin_amdgcn_mfma_f32_16x16x32_bf16(a3, wr[t * 4 + 3], acc[t], 0, 0, 0);

      if (koc < 2) {
#pragma unroll
        for (int t = 0; t < 6; ++t)
#pragma unroll
          for (int qq = 0; qq < 4; ++qq)
            ghp[kw][koc * 4 + qq][t * 16 + row16] = acc[t][qq];
      }
      __syncthreads();

      if (gat) {
        float ghr = 0.f, ghz = 0.f, ghn = 0.f;
#pragma unroll
        for (int k2 = 0; k2 < 8; ++k2) {
          ghr += ghp[k2][bb_l][uu_l];
          ghz += ghp[k2][bb_l][32 + uu_l];
          ghn += ghp[k2][bb_l][64 + uu_l];
        }
        float ir, iz, inn;
        if (gi_is_f32) { ir = girA; iz = gizA; inn = ginA; }
        else { ir = bf2f(r16A); iz = bf2f(z16A); inn = bf2f(n16A); }
        float r = 1.f / (1.f + __expf(-(ir + ghr + bh_r)));
        float z = 1.f / (1.f + __expf(-(iz + ghz + bh_z)));
        float n = tanhf(inn + r * (ghn + bh_n));
        float h = (1.f - z) * n + z * hprevA;
        hprevA = h;
        int bb = bA + bb_l;
        unsigned short hb = f2bf(h);
        unsigned long long sha = (unsigned long long)hout + (unsigned)(bb * 1024 + jg) * 2u;
        asm volatile("global_store_short %0, %1, off sc0 sc1" :: "v"(sha), "v"(hb) : "memory");
        out[((size_t)bb * SEQ + s) * HID + jg] = h;
        if (s == SEQ - 1) hidden[(size_t)bb * HID + jg] = h;
      }
      asm volatile("s_waitcnt vmcnt(1)" ::: "memory");
      __syncthreads();
      if (tid == 0) {
        unsigned a = __hip_atomic_fetch_add(&cA[(g * 4 + half) * 32], 1u, __ATOMIC_RELAXED, __HIP_MEMORY_SCOPE_AGENT);
        if (a + 1u == 16u * (unsigned)(s + 1))
          __hip_atomic_store(&genv[(g * 2 + 0) * 32 + half], (unsigned)(s + 1), __ATOMIC_RELAXED, __HIP_MEMORY_SCOPE_AGENT);
      }
    }

    // ---- wait B (latency hidden under A's compute) ----
    if (tid == 0) {
      unsigned long long gva = (unsigned long long)(genv + (g * 2 + 1) * 32);
      for (;;) {
        uint2 gg;
        asm volatile("global_load_dwordx2 %0, %1, off sc0 sc1\n\ts_waitcnt vmcnt(0)"
                     : "=v"(gg) : "v"(gva) : "memory");
        if (umin2(gg.x, gg.y) >= (unsigned)s) break;
      }
    }
    __syncthreads();

    // ---- sub B: compute + store + arrive ----
    {
      unsigned long long hadr = (unsigned long long)hin + hvB;
      f32x4 acc[6] = {};
      s16x8 a0, a1, a2, a3;
      LDH(a0, "0"); LDH(a1, "64"); LDH(a2, "128"); LDH(a3, "192");
      WAITV(3);
#pragma unroll
      for (int t = 0; t < 6; ++t) acc[t] = __builtin_amdgcn_mfma_f32_16x16x32_bf16(a0, wr[t * 4 + 0], acc[t], 0, 0, 0);
      WAITV(2);
#pragma unroll
      for (int t = 0; t < 6; ++t) acc[t] = __builtin_amdgcn_mfma_f32_16x16x32_bf16(a1, wr[t * 4 + 1], acc[t], 0, 0, 0);
      WAITV(1);
#pragma unroll
      for (int t = 0; t < 6; ++t) acc[t] = __builtin_amdgcn_mfma_f32_16x16x32_bf16(a2, wr[t * 4 + 2], acc[t], 0, 0, 0);
      WAITV(0);
#pragma unroll
      for (int t = 0; t < 6; ++t) acc[t] = __builtin_amdgcn_mfma_f32_16x16x32_bf16(a3, wr[t * 4 + 3], acc[t], 0, 0, 0);

      if (koc < 2) {
#pragma unroll
        for (int t = 0; t < 6; ++t)
#pragma unroll
          for (int qq = 0; qq < 4; ++qq)
            ghp[kw][koc * 4 + qq][t * 16 + row16] = acc[t][qq];
      }
      __syncthreads();

      if (gat) {
        float ghr = 0.f, ghz = 0.f, ghn = 0.f;
#pragma unroll
        for (int k2 = 0; k2 < 8; ++k2) {
          ghr += ghp[k2][bb_l][uu_l];
          ghz += ghp[k2][bb_l][32 + uu_l];
          ghn += ghp[k2][bb_l][64 + uu_l];
        }
        float ir, iz, inn;
        if (gi_is_f32) { ir = girB; iz = gizB; inn = ginB; }
        else { ir = bf2f(r16B); iz = bf2f(z16B); inn = bf2f(n16B); }
        float r = 1.f / (1.f + __expf(-(ir + ghr + bh_r)));
        float z = 1.f / (1.f + __expf(-(iz + ghz + bh_z)));
        float n = tanhf(inn + r * (ghn + bh_n));
        float h = (1.f - z) * n + z * hprevB;
        hprevB = h;
        int bb = bB + bb_l;
        unsigned short hb = f2bf(h);
        unsigned long long sha = (unsigned long long)hout + (unsigned)(bb * 1024 + jg) * 2u;
        asm volatile("global_store_short %0, %1, off sc0 sc1" :: "v"(sha), "v"(hb) : "memory");
        out[((size_t)bb * SEQ + s) * HID + jg] = h;
        if (s == SEQ - 1) hidden[(size_t)bb * HID + jg] = h;
      }
      asm volatile("s_waitcnt vmcnt(1)" ::: "memory");
      __syncthreads();
      if (tid == 0) {
        unsigned a = __hip_atomic_fetch_add(&cA[(g * 4 + 2 + half) * 32], 1u, __ATOMIC_RELAXED, __HIP_MEMORY_SCOPE_AGENT);
        if (a + 1u == 16u * (unsigned)(s + 1))
          __hip_atomic_store(&genv[(g * 2 + 1) * 32 + half], (unsigned)(s + 1), __ATOMIC_RELAXED, __HIP_MEMORY_SCOPE_AGENT);
      }
    }
  }
}

extern "C" void kernel_launch(void* const* d_in, const int* in_sizes, int n_in,
                              void* d_out, int out_size, void* d_ws, size_t ws_size,
                              hipStream_t stream) {
  const float* emb = (const float*)d_in[0];
  const float* wih = (const float*)d_in[1];
  const float* whh = (const float*)d_in[2];
  const float* bih = (const float*)d_in[3];
  const float* bhh = (const float*)d_in[4];
  float* out = (float*)d_out;                          // [64][512][1024]
  float* hidden = out + (size_t)BATCH * SEQ * HID;     // [64][1024]

  char* ws = (char*)d_ws;
  size_t off = 0;
  auto alloc = [&](size_t bytes) {
    char* p = ws + off;
    off += (bytes + 255) & ~(size_t)255;
    return p;
  };

  unsigned short* emb_hi = (unsigned short*)alloc((size_t)MTOT * IN_DIM * 2);
  unsigned short* emb_lo = (unsigned short*)alloc((size_t)MTOT * IN_DIM * 2);
  unsigned short* wih_hi = (unsigned short*)alloc((size_t)G3 * IN_DIM * 2);
  unsigned short* wih_lo = (unsigned short*)alloc((size_t)G3 * IN_DIM * 2);
  unsigned short* whh_hi = (unsigned short*)alloc((size_t)G3 * HID * 2);
  unsigned short* whh_lo = (unsigned short*)alloc((size_t)G3 * HID * 2);
  unsigned short* hbuf   = (unsigned short*)alloc((size_t)2 * BATCH * HID * 2);
  unsigned* bar = (unsigned*)alloc(8192);

  size_t gi32_bytes = (size_t)MTOT * G3 * 4;
  int gi_is_f32 = (off + gi32_bytes <= ws_size) ? 1 : 0;
  float* gi32 = nullptr;
  unsigned short* gi16 = nullptr;
  if (gi_is_f32) gi32 = (float*)alloc(gi32_bytes);
  else           gi16 = (unsigned short*)alloc((size_t)MTOT * G3 * 2);

  // converts
  split_kernel<<<4096, 256, 0, stream>>>(emb, emb_hi, emb_lo, MTOT * IN_DIM / 4);
  split_kernel<<<1536, 256, 0, stream>>>(wih, wih_hi, wih_lo, G3 * IN_DIM / 4);
  split_kernel<<<3072, 256, 0, stream>>>(whh, whh_hi, whh_lo, G3 * HID / 4);

  // zero h state + all counters (must reset every call/replay)
  (void)hipMemsetAsync(hbuf, 0, (size_t)2 * BATCH * HID * 2, stream);
  (void)hipMemsetAsync(bar, 0, 8192, stream);

  // fused cooperative launch: 128 scan WGs + 128 gemm workers, 1 WG/CU
  size_t BH = (size_t)BATCH * HID;
  unsigned short* h0 = hbuf;
  unsigned short* h1 = hbuf + BH;
  void* args[] = { &whh_hi, &emb_hi, &emb_lo, &wih_hi, &wih_lo, &bih,
                   &gi32, &gi16, &gi_is_f32, &bhh,
                   &h0, &h1, &bar, &out, &hidden };
  (void)hipLaunchCooperativeKernel((void*)gru_fused, dim3(256), dim3(512), args, 0, stream);
}

// Round 17
// 2214.645 us; speedup vs baseline: 1.4431x; 1.4431x over previous
//
#include <hip/hip_runtime.h>
#include <hip/hip_bf16.h>

#define SEQ 512
#define BATCH 64
#define IN_DIM 512
#define HID 1024
#define G3 3072          // 3*HID
#define MTOT 32768       // SEQ*BATCH
#define GB 16            // batches per group (4 groups)
#define UPW 32           // hidden units per WG

typedef float f32x4 __attribute__((ext_vector_type(4)));
typedef short s16x8 __attribute__((ext_vector_type(8)));

static __device__ __forceinline__ unsigned short f2bf(float f) {
  union { float f; unsigned u; } v; v.f = f;
  unsigned r = v.u + 0x7fffu + ((v.u >> 16) & 1u);
  return (unsigned short)(r >> 16);
}
static __device__ __forceinline__ float bf2f(unsigned short b) {
  union { unsigned u; float f; } v; v.u = ((unsigned)b) << 16;
  return v.f;
}
static __device__ __forceinline__ unsigned umin2(unsigned a, unsigned b) { return a < b ? a : b; }

// ---------------- fp32 -> bf16 hi/lo split ----------------
__global__ __launch_bounds__(256) void split_kernel(const float* __restrict__ src,
    unsigned short* __restrict__ hi, unsigned short* __restrict__ lo, int n4) {
  int stride = gridDim.x * blockDim.x;
  for (int i = blockIdx.x * blockDim.x + threadIdx.x; i < n4; i += stride) {
    float4 v = ((const float4*)src)[i];
    ushort4 h, l;
    h.x = f2bf(v.x); l.x = f2bf(v.x - bf2f(h.x));
    h.y = f2bf(v.y); l.y = f2bf(v.y - bf2f(h.y));
    h.z = f2bf(v.z); l.z = f2bf(v.z - bf2f(h.z));
    h.w = f2bf(v.w); l.w = f2bf(v.w - bf2f(h.w));
    ((ushort4*)hi)[i] = h;
    ((ushort4*)lo)[i] = l;
  }
}

// ---------------- fused cooperative kernel ----------------
// 256 WGs x 512 thr, 1 WG/CU (LDS pin). Roles by blockIdx (round-14 proven):
//   WGs 0-127: batch-partitioned scan (4 groups x 32 WGs, group owns 16
//   batches, WG owns 32 units, waves K-split 8x128, W in VGPRs).
//   WGs 128-255: gi GEMM workers, s-major jobs; slab bm ready when cnt[bm]==24.
// Barrier (round-17): NO gen relay. Arrive = one relaxed fetch_add on the
// sub-counter (16 WGs each). Poll = read BOTH sub-counters directly
// (monotonic: value >= 16*s means all arrived step s-1). Saves one L3 hop
// per step vs round 14. Slab cnt checked only on even steps (slab = 2 steps).

#define LDH(dst, OFFS) asm volatile("global_load_dwordx4 %0, %1, off offset:" OFFS " sc0 sc1" : "=v"(dst) : "v"(hadr))
#define WAITV(N) do { asm volatile("s_waitcnt vmcnt(" #N ")" ::: "memory"); __builtin_amdgcn_sched_barrier(0); } while (0)

__global__ __launch_bounds__(512, 2) void gru_fused(
    const unsigned short* __restrict__ Whh_hi,
    const unsigned short* __restrict__ emb_hi, const unsigned short* __restrict__ emb_lo,
    const unsigned short* __restrict__ wih_hi, const unsigned short* __restrict__ wih_lo,
    const float* __restrict__ bih,
    float* __restrict__ gi32, unsigned short* __restrict__ gi16, int gi_is_f32,
    const float* __restrict__ bhh,
    unsigned short* __restrict__ h0, unsigned short* __restrict__ h1,
    unsigned* __restrict__ bar,
    float* __restrict__ out, float* __restrict__ hidden)
{
  __shared__ float ghp[8][16][100];        // 50KB (scan role)
  __shared__ unsigned short Ah[128 * 64];  // 4x16KB (gemm role)
  __shared__ unsigned short Alo_[128 * 64];
  __shared__ unsigned short Bh[128 * 64];
  __shared__ unsigned short Blo_[128 * 64];   // ~114KB total -> 1 WG/CU
  const int tid = threadIdx.x;
  const int wg = blockIdx.x;
  const int wave = tid >> 6, lane = tid & 63;
  const int row16 = lane & 15;

  unsigned* cnt = bar;                 // cnt[0..255] slab counters
  unsigned* cA = bar + 256;            // 8 arrive counters, 128B apart

  if (wg >= 128) {
    // ================= GEMM worker role (identical to round 14) ============
    const int widx = wg - 128;
    const int wm = (wave >> 2) * 64, wn = (wave & 3) * 32;
    const int kq = lane >> 4;
    const int srow = tid >> 3;     // 0..63
    const int skc = tid & 7;       // 16B chunk in 128B row

    for (int it = 0; it < 48; ++it) {
      int q = widx + it * 128;
      int bm = q / 24, bn = q - bm * 24;
      int bm0 = bm * 128, bn0 = bn * 128;

      f32x4 acc[4][2] = {};
      for (int kt = 0; kt < IN_DIM / 64; ++kt) {
        uint4 rah[2], ral[2], rbh[2], rbl[2];
        for (int i = 0; i < 2; ++i) {
          int r = i * 64 + srow;
          size_t ao = (size_t)(bm0 + r) * IN_DIM + kt * 64 + skc * 8;
          size_t bo = (size_t)(bn0 + r) * IN_DIM + kt * 64 + skc * 8;
          rah[i] = *(const uint4*)&emb_hi[ao];
          ral[i] = *(const uint4*)&emb_lo[ao];
          rbh[i] = *(const uint4*)&wih_hi[bo];
          rbl[i] = *(const uint4*)&wih_lo[bo];
        }
        __syncthreads();
        for (int i = 0; i < 2; ++i) {
          int r = i * 64 + srow;
          *(uint4*)&Ah[r * 64 + skc * 8]   = rah[i];
          *(uint4*)&Alo_[r * 64 + skc * 8] = ral[i];
          *(uint4*)&Bh[r * 64 + skc * 8]   = rbh[i];
          *(uint4*)&Blo_[r * 64 + skc * 8] = rbl[i];
        }
        __syncthreads();
        for (int kk = 0; kk < 2; ++kk) {
          s16x8 ah[4], al[4], bh[2], bl[2];
          for (int mi = 0; mi < 4; ++mi) {
            int off = (wm + mi * 16 + row16) * 64 + kk * 32 + kq * 8;
            ah[mi] = *(const s16x8*)&Ah[off];
            al[mi] = *(const s16x8*)&Alo_[off];
          }
          for (int ni = 0; ni < 2; ++ni) {
            int off = (wn + ni * 16 + row16) * 64 + kk * 32 + kq * 8;
            bh[ni] = *(const s16x8*)&Bh[off];
            bl[ni] = *(const s16x8*)&Blo_[off];
          }
          for (int mi = 0; mi < 4; ++mi)
            for (int ni = 0; ni < 2; ++ni) {
              acc[mi][ni] = __builtin_amdgcn_mfma_f32_16x16x32_bf16(ah[mi], bh[ni], acc[mi][ni], 0, 0, 0);
              acc[mi][ni] = __builtin_amdgcn_mfma_f32_16x16x32_bf16(al[mi], bh[ni], acc[mi][ni], 0, 0, 0);
              acc[mi][ni] = __builtin_amdgcn_mfma_f32_16x16x32_bf16(ah[mi], bl[ni], acc[mi][ni], 0, 0, 0);
            }
        }
      }
      // epilogue: sc0sc1 write-through stores (visible at coherent point)
      for (int mi = 0; mi < 4; ++mi) {
        int grow0 = bm0 + wm + mi * 16 + kq * 4;
        for (int ni = 0; ni < 2; ++ni) {
          int gcol = bn0 + wn + ni * 16 + row16;
          float bias = bih[gcol];
#pragma unroll
          for (int qq = 0; qq < 4; ++qq) {
            float v = acc[mi][ni][qq] + bias;
            size_t off = (size_t)(grow0 + qq) * G3 + gcol;
            if (gi_is_f32) {
              unsigned long long ad = (unsigned long long)(gi32 + off);
              asm volatile("global_store_dword %0, %1, off sc0 sc1" :: "v"(ad), "v"(v) : "memory");
            } else {
              unsigned short bv = f2bf(v);
              unsigned long long ad = (unsigned long long)(gi16 + off);
              asm volatile("global_store_short %0, %1, off sc0 sc1" :: "v"(ad), "v"(bv) : "memory");
            }
          }
        }
      }
      asm volatile("s_waitcnt vmcnt(0)" ::: "memory");
      __syncthreads();   // whole WG's stores acked
      if (tid == 0)
        __hip_atomic_fetch_add(&cnt[bm], 1u, __ATOMIC_RELAXED, __HIP_MEMORY_SCOPE_AGENT);
    }
    return;
  }

  // ================= scan role (round-13/14 structure) =================
  const int g = wg >> 5, w = wg & 31;
  const int j0 = w * UPW;
  const int b0 = g * GB;
  const int kw = wave;
  const int koc = lane >> 4;

  // hoist this lane's W fragments: 6 col-tiles x 4 k-chunks, global -> VGPR
  s16x8 wr[24];
#pragma unroll
  for (int t = 0; t < 6; ++t) {
#pragma unroll
    for (int ck = 0; ck < 4; ++ck) {
      int wrow = (t >> 1) * HID + j0 + (t & 1) * 16 + row16;
      size_t byte = (size_t)wrow * 2048 + (size_t)(kw * 256 + ck * 64 + koc * 16);
      wr[t * 4 + ck] = *(const s16x8*)((const char*)Whh_hi + byte);
    }
  }

  const unsigned hvoff = (unsigned)((b0 + row16) * 2048 + kw * 256 + koc * 16);
  const int bb_l = tid >> 5, uu_l = tid & 31;
  const int bb = b0 + bb_l, j = j0 + uu_l;
  const float bh_r = bhh[j], bh_z = bhh[HID + j], bh_n = bhh[2 * HID + j];
  float hprev = 0.f;
  const int sub = w >> 4;

  for (int s = 0; s < SEQ; ++s) {
    const unsigned short* hin = (s & 1) ? h1 : h0;
    unsigned short* hout = (s & 1) ? h0 : h1;
    unsigned long long hadr = (unsigned long long)hin + hvoff;

    // wait: slab cnt (even s only, monotonic) + BOTH arrive sub-counters
    // (counter >= 16*s <=> all 16 WGs of that sub finished step s-1)
    if (tid == 0) {
      if ((s & 1) == 0) {
        unsigned long long cva = (unsigned long long)(cnt + (s >> 1));
        for (;;) {
          unsigned cc;
          asm volatile("global_load_dword %0, %1, off sc0 sc1\n\ts_waitcnt vmcnt(0)"
                       : "=v"(cc) : "v"(cva) : "memory");
          if (cc >= 24u) break;
        }
      }
      unsigned long long ava = (unsigned long long)(cA + (g * 2) * 32);
      const unsigned need = 16u * (unsigned)s;
      for (;;) {
        unsigned c0, c1;
        asm volatile("global_load_dword %0, %2, off sc0 sc1\n\t"
                     "global_load_dword %1, %2, off offset:128 sc0 sc1\n\t"
                     "s_waitcnt vmcnt(0)"
                     : "=v"(c0), "=v"(c1) : "v"(ava) : "memory");
        if (c0 >= need && c1 >= need) break;
      }
    }
    __syncthreads();

    // gi loads (slab gated) -- issued first, retire inside WAITV(3)
    float gir = 0.f, giz = 0.f, gin_ = 0.f;
    unsigned short g16r = 0, g16z = 0, g16n = 0;
    if (gi_is_f32) {
      unsigned long long ga = (unsigned long long)(gi32 + (size_t)(s * BATCH + bb) * G3 + j);
      asm volatile("global_load_dword %0, %1, off sc0 sc1" : "=v"(gir) : "v"(ga));
      asm volatile("global_load_dword %0, %1, off sc0 sc1" : "=v"(giz) : "v"(ga + 4096ull));
      asm volatile("global_load_dword %0, %1, off sc0 sc1" : "=v"(gin_) : "v"(ga + 8192ull));
    } else {
      unsigned long long ga = (unsigned long long)(gi16 + (size_t)(s * BATCH + bb) * G3 + j);
      asm volatile("global_load_ushort %0, %1, off sc0 sc1" : "=v"(g16r) : "v"(ga));
      asm volatile("global_load_ushort %0, %1, off sc0 sc1" : "=v"(g16z) : "v"(ga + 2048ull));
      asm volatile("global_load_ushort %0, %1, off sc0 sc1" : "=v"(g16n) : "v"(ga + 4096ull));
    }

    // h loads (4 x dwordx4) + MFMA from registers
    f32x4 acc[6] = {};
    s16x8 a0, a1, a2, a3;
    LDH(a0, "0"); LDH(a1, "64"); LDH(a2, "128"); LDH(a3, "192");
    WAITV(3);
#pragma unroll
    for (int t = 0; t < 6; ++t) acc[t] = __builtin_amdgcn_mfma_f32_16x16x32_bf16(a0, wr[t * 4 + 0], acc[t], 0, 0, 0);
    WAITV(2);
#pragma unroll
    for (int t = 0; t < 6; ++t) acc[t] = __builtin_amdgcn_mfma_f32_16x16x32_bf16(a1, wr[t * 4 + 1], acc[t], 0, 0, 0);
    WAITV(1);
#pragma unroll
    for (int t = 0; t < 6; ++t) acc[t] = __builtin_amdgcn_mfma_f32_16x16x32_bf16(a2, wr[t * 4 + 2], acc[t], 0, 0, 0);
    WAITV(0);
#pragma unroll
    for (int t = 0; t < 6; ++t) acc[t] = __builtin_amdgcn_mfma_f32_16x16x32_bf16(a3, wr[t * 4 + 3], acc[t], 0, 0, 0);

#pragma unroll
    for (int t = 0; t < 6; ++t)
#pragma unroll
      for (int qq = 0; qq < 4; ++qq)
        ghp[kw][koc * 4 + qq][t * 16 + row16] = acc[t][qq];
    __syncthreads();

    // reduce 8 K-partials + gating
    float ghr = 0.f, ghz = 0.f, ghn = 0.f;
#pragma unroll
    for (int k2 = 0; k2 < 8; ++k2) {
      ghr += ghp[k2][bb_l][uu_l];
      ghz += ghp[k2][bb_l][32 + uu_l];
      ghn += ghp[k2][bb_l][64 + uu_l];
    }
    float ir, iz, inn;
    if (gi_is_f32) { ir = gir; iz = giz; inn = gin_; }
    else { ir = bf2f(g16r); iz = bf2f(g16z); inn = bf2f(g16n); }
    float r = 1.f / (1.f + __expf(-(ir + ghr + bh_r)));
    float z = 1.f / (1.f + __expf(-(iz + ghz + bh_z)));
    float n = tanhf(inn + r * (ghn + bh_n));
    float h = (1.f - z) * n + z * hprev;
    hprev = h;
    unsigned short hb = f2bf(h);
    unsigned long long sha = (unsigned long long)hout + (unsigned)(bb * 1024 + j) * 2u;
    asm volatile("global_store_short %0, %1, off sc0 sc1" :: "v"(sha), "v"(hb) : "memory");
    out[((size_t)bb * SEQ + s) * HID + j] = h;
    if (s == SEQ - 1) hidden[(size_t)bb * HID + j] = h;
    asm volatile("s_waitcnt vmcnt(1)" ::: "memory");
    __syncthreads();   // h acked + ghp reuse guard

    // arrive: one relaxed RMW; the counter VALUE is the barrier signal
    if (tid == 0)
      __hip_atomic_fetch_add(&cA[(g * 2 + sub) * 32], 1u, __ATOMIC_RELAXED, __HIP_MEMORY_SCOPE_AGENT);
  }
}

extern "C" void kernel_launch(void* const* d_in, const int* in_sizes, int n_in,
                              void* d_out, int out_size, void* d_ws, size_t ws_size,
                              hipStream_t stream) {
  const float* emb = (const float*)d_in[0];
  const float* wih = (const float*)d_in[1];
  const float* whh = (const float*)d_in[2];
  const float* bih = (const float*)d_in[3];
  const float* bhh = (const float*)d_in[4];
  float* out = (float*)d_out;                          // [64][512][1024]
  float* hidden = out + (size_t)BATCH * SEQ * HID;     // [64][1024]

  char* ws = (char*)d_ws;
  size_t off = 0;
  auto alloc = [&](size_t bytes) {
    char* p = ws + off;
    off += (bytes + 255) & ~(size_t)255;
    return p;
  };

  unsigned short* emb_hi = (unsigned short*)alloc((size_t)MTOT * IN_DIM * 2);
  unsigned short* emb_lo = (unsigned short*)alloc((size_t)MTOT * IN_DIM * 2);
  unsigned short* wih_hi = (unsigned short*)alloc((size_t)G3 * IN_DIM * 2);
  unsigned short* wih_lo = (unsigned short*)alloc((size_t)G3 * IN_DIM * 2);
  unsigned short* whh_hi = (unsigned short*)alloc((size_t)G3 * HID * 2);
  unsigned short* whh_lo = (unsigned short*)alloc((size_t)G3 * HID * 2);
  unsigned short* hbuf   = (unsigned short*)alloc((size_t)2 * BATCH * HID * 2);
  unsigned* bar = (unsigned*)alloc(8192);

  size_t gi32_bytes = (size_t)MTOT * G3 * 4;
  int gi_is_f32 = (off + gi32_bytes <= ws_size) ? 1 : 0;
  float* gi32 = nullptr;
  unsigned short* gi16 = nullptr;
  if (gi_is_f32) gi32 = (float*)alloc(gi32_bytes);
  else           gi16 = (unsigned short*)alloc((size_t)MTOT * G3 * 2);

  // converts
  split_kernel<<<4096, 256, 0, stream>>>(emb, emb_hi, emb_lo, MTOT * IN_DIM / 4);
  split_kernel<<<1536, 256, 0, stream>>>(wih, wih_hi, wih_lo, G3 * IN_DIM / 4);
  split_kernel<<<3072, 256, 0, stream>>>(whh, whh_hi, whh_lo, G3 * HID / 4);

  // zero h state + all counters (must reset every call/replay)
  (void)hipMemsetAsync(hbuf, 0, (size_t)2 * BATCH * HID * 2, stream);
  (void)hipMemsetAsync(bar, 0, 8192, stream);

  // fused cooperative launch: 128 scan WGs + 128 gemm workers, 1 WG/CU
  size_t BH = (size_t)BATCH * HID;
  unsigned short* h0 = hbuf;
  unsigned short* h1 = hbuf + BH;
  void* args[] = { &whh_hi, &emb_hi, &emb_lo, &wih_hi, &wih_lo, &bih,
                   &gi32, &gi16, &gi_is_f32, &bhh,
                   &h0, &h1, &bar, &out, &hidden };
  (void)hipLaunchCooperativeKernel((void*)gru_fused, dim3(256), dim3(512), args, 0, stream);
}

// Round 18
// 2064.144 us; speedup vs baseline: 1.5484x; 1.0729x over previous
//
#include <hip/hip_runtime.h>
#include <hip/hip_bf16.h>

#define SEQ 512
#define BATCH 64
#define IN_DIM 512
#define HID 1024
#define G3 3072          // 3*HID
#define MTOT 32768       // SEQ*BATCH
#define GB 16            // batches per group (4 groups)
#define UPW 32           // hidden units per WG

typedef float f32x4 __attribute__((ext_vector_type(4)));
typedef short s16x8 __attribute__((ext_vector_type(8)));

static __device__ __forceinline__ unsigned short f2bf(float f) {
  union { float f; unsigned u; } v; v.f = f;
  unsigned r = v.u + 0x7fffu + ((v.u >> 16) & 1u);
  return (unsigned short)(r >> 16);
}
static __device__ __forceinline__ float bf2f(unsigned short b) {
  union { unsigned u; float f; } v; v.u = ((unsigned)b) << 16;
  return v.f;
}
static __device__ __forceinline__ unsigned umin2(unsigned a, unsigned b) { return a < b ? a : b; }

// ---------------- fp32 -> bf16 hi/lo split ----------------
__global__ __launch_bounds__(256) void split_kernel(const float* __restrict__ src,
    unsigned short* __restrict__ hi, unsigned short* __restrict__ lo, int n4) {
  int stride = gridDim.x * blockDim.x;
  for (int i = blockIdx.x * blockDim.x + threadIdx.x; i < n4; i += stride) {
    float4 v = ((const float4*)src)[i];
    ushort4 h, l;
    h.x = f2bf(v.x); l.x = f2bf(v.x - bf2f(h.x));
    h.y = f2bf(v.y); l.y = f2bf(v.y - bf2f(h.y));
    h.z = f2bf(v.z); l.z = f2bf(v.z - bf2f(h.z));
    h.w = f2bf(v.w); l.w = f2bf(v.w - bf2f(h.w));
    ((ushort4*)hi)[i] = h;
    ((ushort4*)lo)[i] = l;
  }
}

// ---------------- fused cooperative kernel ----------------
// 256 WGs x 512 thr, 1 WG/CU (LDS pin). Roles by blockIdx (round-14 proven):
//   WGs 0-127: batch-partitioned scan (4 groups x 32 WGs; group owns 16
//   batches, WG owns 32 units, waves K-split 8x128, W in VGPRs).
//   WGs 128-255: gi GEMM workers, s-major jobs; slab bm ready when cnt[bm]==24.
// Barrier (round-18): round-14 shape, fan-in halved. 4 subs x 8 WGs per
// group; 8th arriver of sub writes genv[g*32+sub]; poll = one dwordx4 of the
// gen quad + cnt dword (single round-trip). RMW serialization per line 16->8.

#define LDH(dst, OFFS) asm volatile("global_load_dwordx4 %0, %1, off offset:" OFFS " sc0 sc1" : "=v"(dst) : "v"(hadr))
#define WAITV(N) do { asm volatile("s_waitcnt vmcnt(" #N ")" ::: "memory"); __builtin_amdgcn_sched_barrier(0); } while (0)

__global__ __launch_bounds__(512, 2) void gru_fused(
    const unsigned short* __restrict__ Whh_hi,
    const unsigned short* __restrict__ emb_hi, const unsigned short* __restrict__ emb_lo,
    const unsigned short* __restrict__ wih_hi, const unsigned short* __restrict__ wih_lo,
    const float* __restrict__ bih,
    float* __restrict__ gi32, unsigned short* __restrict__ gi16, int gi_is_f32,
    const float* __restrict__ bhh,
    unsigned short* __restrict__ h0, unsigned short* __restrict__ h1,
    unsigned* __restrict__ bar,
    float* __restrict__ out, float* __restrict__ hidden)
{
  __shared__ float ghp[8][16][100];        // 50KB (scan role)
  __shared__ unsigned short Ah[128 * 64];  // 4x16KB (gemm role)
  __shared__ unsigned short Alo_[128 * 64];
  __shared__ unsigned short Bh[128 * 64];
  __shared__ unsigned short Blo_[128 * 64];   // ~114KB total -> 1 WG/CU
  const int tid = threadIdx.x;
  const int wg = blockIdx.x;
  const int wave = tid >> 6, lane = tid & 63;
  const int row16 = lane & 15;

  unsigned* cnt = bar;                 // cnt[0..255] slab counters
  unsigned* cA = bar + 256;            // 16 arrive counters, 128B apart
  unsigned* genv = bar + 2816;         // gen quads: genv[g*32 + sub], 128B/group

  if (wg >= 128) {
    // ================= GEMM worker role (identical to round 14) ============
    const int widx = wg - 128;
    const int wm = (wave >> 2) * 64, wn = (wave & 3) * 32;
    const int kq = lane >> 4;
    const int srow = tid >> 3;     // 0..63
    const int skc = tid & 7;       // 16B chunk in 128B row

    for (int it = 0; it < 48; ++it) {
      int q = widx + it * 128;
      int bm = q / 24, bn = q - bm * 24;
      int bm0 = bm * 128, bn0 = bn * 128;

      f32x4 acc[4][2] = {};
      for (int kt = 0; kt < IN_DIM / 64; ++kt) {
        uint4 rah[2], ral[2], rbh[2], rbl[2];
        for (int i = 0; i < 2; ++i) {
          int r = i * 64 + srow;
          size_t ao = (size_t)(bm0 + r) * IN_DIM + kt * 64 + skc * 8;
          size_t bo = (size_t)(bn0 + r) * IN_DIM + kt * 64 + skc * 8;
          rah[i] = *(const uint4*)&emb_hi[ao];
          ral[i] = *(const uint4*)&emb_lo[ao];
          rbh[i] = *(const uint4*)&wih_hi[bo];
          rbl[i] = *(const uint4*)&wih_lo[bo];
        }
        __syncthreads();
        for (int i = 0; i < 2; ++i) {
          int r = i * 64 + srow;
          *(uint4*)&Ah[r * 64 + skc * 8]   = rah[i];
          *(uint4*)&Alo_[r * 64 + skc * 8] = ral[i];
          *(uint4*)&Bh[r * 64 + skc * 8]   = rbh[i];
          *(uint4*)&Blo_[r * 64 + skc * 8] = rbl[i];
        }
        __syncthreads();
        for (int kk = 0; kk < 2; ++kk) {
          s16x8 ah[4], al[4], bh[2], bl[2];
          for (int mi = 0; mi < 4; ++mi) {
            int off = (wm + mi * 16 + row16) * 64 + kk * 32 + kq * 8;
            ah[mi] = *(const s16x8*)&Ah[off];
            al[mi] = *(const s16x8*)&Alo_[off];
          }
          for (int ni = 0; ni < 2; ++ni) {
            int off = (wn + ni * 16 + row16) * 64 + kk * 32 + kq * 8;
            bh[ni] = *(const s16x8*)&Bh[off];
            bl[ni] = *(const s16x8*)&Blo_[off];
          }
          for (int mi = 0; mi < 4; ++mi)
            for (int ni = 0; ni < 2; ++ni) {
              acc[mi][ni] = __builtin_amdgcn_mfma_f32_16x16x32_bf16(ah[mi], bh[ni], acc[mi][ni], 0, 0, 0);
              acc[mi][ni] = __builtin_amdgcn_mfma_f32_16x16x32_bf16(al[mi], bh[ni], acc[mi][ni], 0, 0, 0);
              acc[mi][ni] = __builtin_amdgcn_mfma_f32_16x16x32_bf16(ah[mi], bl[ni], acc[mi][ni], 0, 0, 0);
            }
        }
      }
      // epilogue: sc0sc1 write-through stores (visible at coherent point)
      for (int mi = 0; mi < 4; ++mi) {
        int grow0 = bm0 + wm + mi * 16 + kq * 4;
        for (int ni = 0; ni < 2; ++ni) {
          int gcol = bn0 + wn + ni * 16 + row16;
          float bias = bih[gcol];
#pragma unroll
          for (int qq = 0; qq < 4; ++qq) {
            float v = acc[mi][ni][qq] + bias;
            size_t off = (size_t)(grow0 + qq) * G3 + gcol;
            if (gi_is_f32) {
              unsigned long long ad = (unsigned long long)(gi32 + off);
              asm volatile("global_store_dword %0, %1, off sc0 sc1" :: "v"(ad), "v"(v) : "memory");
            } else {
              unsigned short bv = f2bf(v);
              unsigned long long ad = (unsigned long long)(gi16 + off);
              asm volatile("global_store_short %0, %1, off sc0 sc1" :: "v"(ad), "v"(bv) : "memory");
            }
          }
        }
      }
      asm volatile("s_waitcnt vmcnt(0)" ::: "memory");
      __syncthreads();   // whole WG's stores acked
      if (tid == 0)
        __hip_atomic_fetch_add(&cnt[bm], 1u, __ATOMIC_RELAXED, __HIP_MEMORY_SCOPE_AGENT);
    }
    return;
  }

  // ================= scan role (round-13/14 structure) =================
  const int g = wg >> 5, w = wg & 31;
  const int j0 = w * UPW;
  const int b0 = g * GB;
  const int kw = wave;
  const int koc = lane >> 4;

  // hoist this lane's W fragments: 6 col-tiles x 4 k-chunks, global -> VGPR
  s16x8 wr[24];
#pragma unroll
  for (int t = 0; t < 6; ++t) {
#pragma unroll
    for (int ck = 0; ck < 4; ++ck) {
      int wrow = (t >> 1) * HID + j0 + (t & 1) * 16 + row16;
      size_t byte = (size_t)wrow * 2048 + (size_t)(kw * 256 + ck * 64 + koc * 16);
      wr[t * 4 + ck] = *(const s16x8*)((const char*)Whh_hi + byte);
    }
  }

  const unsigned hvoff = (unsigned)((b0 + row16) * 2048 + kw * 256 + koc * 16);
  const int bb_l = tid >> 5, uu_l = tid & 31;
  const int bb = b0 + bb_l, j = j0 + uu_l;
  const float bh_r = bhh[j], bh_z = bhh[HID + j], bh_n = bhh[2 * HID + j];
  float hprev = 0.f;
  const int sub = w >> 3;              // 4 subs of 8 WGs

  for (int s = 0; s < SEQ; ++s) {
    const unsigned short* hin = (s & 1) ? h1 : h0;
    unsigned short* hout = (s & 1) ? h0 : h1;
    unsigned long long hadr = (unsigned long long)hin + hvoff;

    // combined wait: gen quad (all 4 subs >= s) + gi slab complete, 1 RT
    if (tid == 0) {
      unsigned long long gva = (unsigned long long)(genv + g * 32);
      unsigned long long cva = (unsigned long long)(cnt + (s >> 1));
      for (;;) {
        uint4 gg; unsigned cc;
        asm volatile("global_load_dwordx4 %0, %2, off sc0 sc1\n\t"
                     "global_load_dword %1, %3, off sc0 sc1\n\t"
                     "s_waitcnt vmcnt(0)"
                     : "=v"(gg), "=v"(cc) : "v"(gva), "v"(cva) : "memory");
        unsigned mn = umin2(umin2(gg.x, gg.y), umin2(gg.z, gg.w));
        if (mn >= (unsigned)s && cc >= 24u) break;
      }
    }
    __syncthreads();

    // gi loads (slab gated) -- issued first, retire inside WAITV(3)
    float gir = 0.f, giz = 0.f, gin_ = 0.f;
    unsigned short g16r = 0, g16z = 0, g16n = 0;
    if (gi_is_f32) {
      unsigned long long ga = (unsigned long long)(gi32 + (size_t)(s * BATCH + bb) * G3 + j);
      asm volatile("global_load_dword %0, %1, off sc0 sc1" : "=v"(gir) : "v"(ga));
      asm volatile("global_load_dword %0, %1, off sc0 sc1" : "=v"(giz) : "v"(ga + 4096ull));
      asm volatile("global_load_dword %0, %1, off sc0 sc1" : "=v"(gin_) : "v"(ga + 8192ull));
    } else {
      unsigned long long ga = (unsigned long long)(gi16 + (size_t)(s * BATCH + bb) * G3 + j);
      asm volatile("global_load_ushort %0, %1, off sc0 sc1" : "=v"(g16r) : "v"(ga));
      asm volatile("global_load_ushort %0, %1, off sc0 sc1" : "=v"(g16z) : "v"(ga + 2048ull));
      asm volatile("global_load_ushort %0, %1, off sc0 sc1" : "=v"(g16n) : "v"(ga + 4096ull));
    }

    // h loads (4 x dwordx4) + MFMA from registers
    f32x4 acc[6] = {};
    s16x8 a0, a1, a2, a3;
    LDH(a0, "0"); LDH(a1, "64"); LDH(a2, "128"); LDH(a3, "192");
    WAITV(3);
#pragma unroll
    for (int t = 0; t < 6; ++t) acc[t] = __builtin_amdgcn_mfma_f32_16x16x32_bf16(a0, wr[t * 4 + 0], acc[t], 0, 0, 0);
    WAITV(2);
#pragma unroll
    for (int t = 0; t < 6; ++t) acc[t] = __builtin_amdgcn_mfma_f32_16x16x32_bf16(a1, wr[t * 4 + 1], acc[t], 0, 0, 0);
    WAITV(1);
#pragma unroll
    for (int t = 0; t < 6; ++t) acc[t] = __builtin_amdgcn_mfma_f32_16x16x32_bf16(a2, wr[t * 4 + 2], acc[t], 0, 0, 0);
    WAITV(0);
#pragma unroll
    for (int t = 0; t < 6; ++t) acc[t] = __builtin_amdgcn_mfma_f32_16x16x32_bf16(a3, wr[t * 4 + 3], acc[t], 0, 0, 0);

#pragma unroll
    for (int t = 0; t < 6; ++t)
#pragma unroll
      for (int qq = 0; qq < 4; ++qq)
        ghp[kw][koc * 4 + qq][t * 16 + row16] = acc[t][qq];
    __syncthreads();

    // reduce 8 K-partials + gating
    float ghr = 0.f, ghz = 0.f, ghn = 0.f;
#pragma unroll
    for (int k2 = 0; k2 < 8; ++k2) {
      ghr += ghp[k2][bb_l][uu_l];
      ghz += ghp[k2][bb_l][32 + uu_l];
      ghn += ghp[k2][bb_l][64 + uu_l];
    }
    float ir, iz, inn;
    if (gi_is_f32) { ir = gir; iz = giz; inn = gin_; }
    else { ir = bf2f(g16r); iz = bf2f(g16z); inn = bf2f(g16n); }
    float r = 1.f / (1.f + __expf(-(ir + ghr + bh_r)));
    float z = 1.f / (1.f + __expf(-(iz + ghz + bh_z)));
    float n = tanhf(inn + r * (ghn + bh_n));
    float h = (1.f - z) * n + z * hprev;
    hprev = h;
    // h store FIRST (gates the barrier), then out/hidden (drain later)
    unsigned short hb = f2bf(h);
    unsigned long long sha = (unsigned long long)hout + (unsigned)(bb * 1024 + j) * 2u;
    asm volatile("global_store_short %0, %1, off sc0 sc1" :: "v"(sha), "v"(hb) : "memory");
    out[((size_t)bb * SEQ + s) * HID + j] = h;
    if (s == SEQ - 1) hidden[(size_t)bb * HID + j] = h;
    asm volatile("s_waitcnt vmcnt(1)" ::: "memory");
    __syncthreads();   // h acked + ghp reuse guard

    // arrive: relaxed monotonic; 8th of sub writes its gen dword
    if (tid == 0) {
      unsigned a = __hip_atomic_fetch_add(&cA[(g * 4 + sub) * 32], 1u, __ATOMIC_RELAXED, __HIP_MEMORY_SCOPE_AGENT);
      if (a + 1u == 8u * (unsigned)(s + 1)) {
        __hip_atomic_store(&genv[g * 32 + sub], (unsigned)(s + 1), __ATOMIC_RELAXED, __HIP_MEMORY_SCOPE_AGENT);
      }
    }
  }
}

extern "C" void kernel_launch(void* const* d_in, const int* in_sizes, int n_in,
                              void* d_out, int out_size, void* d_ws, size_t ws_size,
                              hipStream_t stream) {
  const float* emb = (const float*)d_in[0];
  const float* wih = (const float*)d_in[1];
  const float* whh = (const float*)d_in[2];
  const float* bih = (const float*)d_in[3];
  const float* bhh = (const float*)d_in[4];
  float* out = (float*)d_out;                          // [64][512][1024]
  float* hidden = out + (size_t)BATCH * SEQ * HID;     // [64][1024]

  char* ws = (char*)d_ws;
  size_t off = 0;
  auto alloc = [&](size_t bytes) {
    char* p = ws + off;
    off += (bytes + 255) & ~(size_t)255;
    return p;
  };

  unsigned short* emb_hi = (unsigned short*)alloc((size_t)MTOT * IN_DIM * 2);
  unsigned short* emb_lo = (unsigned short*)alloc((size_t)MTOT * IN_DIM * 2);
  unsigned short* wih_hi = (unsigned short*)alloc((size_t)G3 * IN_DIM * 2);
  unsigned short* wih_lo = (unsigned short*)alloc((size_t)G3 * IN_DIM * 2);
  unsigned short* whh_hi = (unsigned short*)alloc((size_t)G3 * HID * 2);
  unsigned short* whh_lo = (unsigned short*)alloc((size_t)G3 * HID * 2);
  unsigned short* hbuf   = (unsigned short*)alloc((size_t)2 * BATCH * HID * 2);
  unsigned* bar = (unsigned*)alloc(16384);

  size_t gi32_bytes = (size_t)MTOT * G3 * 4;
  int gi_is_f32 = (off + gi32_bytes <= ws_size) ? 1 : 0;
  float* gi32 = nullptr;
  unsigned short* gi16 = nullptr;
  if (gi_is_f32) gi32 = (float*)alloc(gi32_bytes);
  else           gi16 = (unsigned short*)alloc((size_t)MTOT * G3 * 2);

  // converts
  split_kernel<<<4096, 256, 0, stream>>>(emb, emb_hi, emb_lo, MTOT * IN_DIM / 4);
  split_kernel<<<1536, 256, 0, stream>>>(wih, wih_hi, wih_lo, G3 * IN_DIM / 4);
  split_kernel<<<3072, 256, 0, stream>>>(whh, whh_hi, whh_lo, G3 * HID / 4);

  // zero h state + all counters (must reset every call/replay)
  (void)hipMemsetAsync(hbuf, 0, (size_t)2 * BATCH * HID * 2, stream);
  (void)hipMemsetAsync(bar, 0, 16384, stream);

  // fused cooperative launch: 128 scan WGs + 128 gemm workers, 1 WG/CU
  size_t BH = (size_t)BATCH * HID;
  unsigned short* h0 = hbuf;
  unsigned short* h1 = hbuf + BH;
  void* args[] = { &whh_hi, &emb_hi, &emb_lo, &wih_hi, &wih_lo, &bih,
                   &gi32, &gi16, &gi_is_f32, &bhh,
                   &h0, &h1, &bar, &out, &hidden };
  (void)hipLaunchCooperativeKernel((void*)gru_fused, dim3(256), dim3(512), args, 0, stream);
}